// Round 3
// baseline (136.698 us; speedup 1.0000x reference)
//
#include <hip/hip_runtime.h>
#include <math.h>

#define N_ROWS 32768
#define K_CODES 4096
#define DIM 64
#define SPLITS 4
#define TILES_TOTAL (K_CODES / 32)              // 128
#define TILES_PER_SPLIT (TILES_TOTAL / SPLITS)  // 32
#define QUANT_ELEMS (N_ROWS * DIM)              // 2097152

typedef _Float16 half8 __attribute__((ext_vector_type(8)));
typedef float floatx16 __attribute__((ext_vector_type(16)));

// ---------------------------------------------------------------------------
// Kernel 0 (fused): embed -> fp16 hi/lo B-fragments for mfma_f32_32x32x16_f16
// AND per-code squared norms (LDS reduction).
// Tile c = 32 codes; kstep s covers k=16s..16s+15. Thread t = c*256 + s*64 + l
// holds B[k=(l>>5)*8+j+16s][col=l&31] = embed[c*32+(l&31)][(l>>5)*8+j+16s].
// One 256-thread block per tile (grid = 128 blocks).
// ---------------------------------------------------------------------------
__global__ void prep_kernel(const float* __restrict__ embed,
                            float* __restrict__ sq, half8* __restrict__ ehi,
                            half8* __restrict__ elo) {
    __shared__ float part[256];
    const int tid = threadIdx.x;
    const int t = blockIdx.x * 256 + tid;
    const int l = t & 63;
    const int s = (t >> 6) & 3;
    const int c = blockIdx.x;  // == t >> 8
    const int col = l & 31;
    const int code = c * 32 + col;
    const int koff = (l >> 5) * 8 + 16 * s;
    const float* src = embed + (size_t)code * DIM + koff;
    half8 h, lo;
    float ss = 0.f;
#pragma unroll
    for (int j = 0; j < 8; ++j) {
        float v = src[j];
        ss = fmaf(v, v, ss);
        _Float16 hi = (_Float16)v;
        h[j] = hi;
        lo[j] = (_Float16)(v - (float)hi);
    }
    ehi[t] = h;
    elo[t] = lo;
    part[tid] = ss;
    __syncthreads();
    if (tid < 32) {
        // code (c*32 + tid)'s 8 partials live at tid + 32*h + 64*s
        float a = 0.f;
#pragma unroll
        for (int q = 0; q < 8; ++q) a += part[tid + 32 * (q & 1) + 64 * (q >> 1)];
        sq[c * 32 + tid] = a;
    }
}

// ---------------------------------------------------------------------------
// Kernel 1: fused dist(GEMM 32x32x16) + per-split argmax.
// v4: NO LDS, NO barriers. B fragments are loaded global->VGPR directly
// (coalesced dwordx4 from the L2-resident 1MB prepped codebook). v2's
// counters showed the three pipes (MFMA 21us, LDS-read 20us, VALU 27us)
// running SERIALIZED because the per-phase barriers lockstep all waves into
// the same sub-phase. Removing LDS+barriers deletes the LDS pipe entirely
// and lets free-running waves (4/SIMD) overlap VMEM latency, MFMA, and
// argmax VALU across waves.
// Per-tile software pipeline: issue tile-c loads -> argmax tile c-1 (VALU
// hides L2 latency) -> MFMA tile c.
// dist = dot(2x,e) - ||e||^2 ; -||e||^2 = acc init, 2x folded into A (exact).
// fp16 split, 3 terms: xh*eh + xl*eh + xh*el.
// grid = (N_ROWS/128, SPLITS) = (256, 4), block = 256 (4 waves x 32 rows).
// ---------------------------------------------------------------------------
__global__ __launch_bounds__(256, 4) void fused_dist_argmax_g(
    const float* __restrict__ x, const float* __restrict__ sq,
    const half8* __restrict__ ehi, const half8* __restrict__ elo,
    float* __restrict__ pbest, int* __restrict__ pidx) {
    const int tid = threadIdx.x;
    const int lane = tid & 63;
    const int wave = tid >> 6;
    const int col = lane & 31;    // B col (code within tile); A row
    const int half_ = lane >> 5;  // k-half
    const int row_base = blockIdx.x * 128 + wave * 32;
    const int split = blockIdx.y;
    const int c0 = split * TILES_PER_SPLIT;

    // Persistent A fragments (scaled by 2): A[m=col][k=half_*8+j+16s]
    half8 ah[4], al[4];
    {
        const float* xs = x + (size_t)(row_base + col) * DIM + half_ * 8;
#pragma unroll
        for (int s = 0; s < 4; ++s) {
            half8 h, lo;
#pragma unroll
            for (int j = 0; j < 8; ++j) {
                float v = 2.0f * xs[16 * s + j];
                _Float16 hi = (_Float16)v;
                h[j] = hi;
                lo[j] = (_Float16)(v - (float)hi);
            }
            ah[s] = h;
            al[s] = lo;
        }
    }

    float best[16];
    int bidx[16];
#pragma unroll
    for (int r = 0; r < 16; ++r) {
        best[r] = -INFINITY;
        bidx[r] = 0;
    }

    const half8* gh = ehi + (size_t)c0 * 256;
    const half8* gl = elo + (size_t)c0 * 256;
    const float* psq = sq + c0 * 32 + col;

    floatx16 accP;      // acc of previous tile (argmax'd one iteration late)
    int cidxP = 0;      // its code index for this lane's column
    bool haveP = false; // becomes true after first iteration (peeled by hand
                        // via first-iteration predicate; unroll 1 keeps 1 copy)

#pragma unroll 1
    for (int c = 0; c < TILES_PER_SPLIT; ++c) {
        const half8* th = gh + (size_t)c * 256;
        const half8* tl = gl + (size_t)c * 256;
        // Issue all 8 B-fragment loads for tile c (coalesced dwordx4, L2-hot).
        half8 b0 = th[lane];
        half8 b1 = th[64 + lane];
        half8 b2 = th[128 + lane];
        half8 b3 = th[192 + lane];
        half8 l0 = tl[lane];
        half8 l1 = tl[64 + lane];
        half8 l2 = tl[128 + lane];
        half8 l3 = tl[192 + lane];
        const float nsq = -psq[(size_t)c * 32];

        // Argmax of the PREVIOUS tile sits in the L2-latency shadow of the
        // loads above (ascending c order preserved -> tie semantics intact).
        if (haveP) {
#pragma unroll
            for (int r = 0; r < 16; ++r) {
                if (accP[r] > best[r]) {  // strict >: earliest tile wins ties
                    best[r] = accP[r];
                    bidx[r] = cidxP;
                }
            }
        }

        floatx16 acc;
#pragma unroll
        for (int r = 0; r < 16; ++r) acc[r] = nsq;

        __builtin_amdgcn_s_setprio(1);
        acc = __builtin_amdgcn_mfma_f32_32x32x16_f16(ah[0], b0, acc, 0, 0, 0);
        acc = __builtin_amdgcn_mfma_f32_32x32x16_f16(al[0], b0, acc, 0, 0, 0);
        acc = __builtin_amdgcn_mfma_f32_32x32x16_f16(ah[1], b1, acc, 0, 0, 0);
        acc = __builtin_amdgcn_mfma_f32_32x32x16_f16(al[1], b1, acc, 0, 0, 0);
        acc = __builtin_amdgcn_mfma_f32_32x32x16_f16(ah[2], b2, acc, 0, 0, 0);
        acc = __builtin_amdgcn_mfma_f32_32x32x16_f16(al[2], b2, acc, 0, 0, 0);
        acc = __builtin_amdgcn_mfma_f32_32x32x16_f16(ah[3], b3, acc, 0, 0, 0);
        acc = __builtin_amdgcn_mfma_f32_32x32x16_f16(al[3], b3, acc, 0, 0, 0);
        acc = __builtin_amdgcn_mfma_f32_32x32x16_f16(ah[0], l0, acc, 0, 0, 0);
        acc = __builtin_amdgcn_mfma_f32_32x32x16_f16(ah[1], l1, acc, 0, 0, 0);
        acc = __builtin_amdgcn_mfma_f32_32x32x16_f16(ah[2], l2, acc, 0, 0, 0);
        acc = __builtin_amdgcn_mfma_f32_32x32x16_f16(ah[3], l3, acc, 0, 0, 0);
        __builtin_amdgcn_s_setprio(0);

        accP = acc;
        cidxP = (c0 + c) * 32 + col;
        haveP = true;
    }

    // Drain the last tile's argmax.
#pragma unroll
    for (int r = 0; r < 16; ++r) {
        if (accP[r] > best[r]) {
            best[r] = accP[r];
            bidx[r] = cidxP;
        }
    }

    // C/D layout (32x32): col = lane&31, row = (r&3) + 8*(r>>2) + 4*half_.
#pragma unroll
    for (int r = 0; r < 16; ++r) {
        float bv = best[r];
        int bi = bidx[r];
#pragma unroll
        for (int d = 1; d < 32; d <<= 1) {
            float ov = __shfl_xor(bv, d);
            int oi = __shfl_xor(bi, d);
            if (ov > bv || (ov == bv && oi < bi)) {  // smaller idx on tie
                bv = ov;
                bi = oi;
            }
        }
        if (col == 0) {
            const int row = row_base + (r & 3) + 8 * (r >> 2) + 4 * half_;
            pbest[(size_t)split * N_ROWS + row] = bv;
            pidx[(size_t)split * N_ROWS + row] = bi;
        }
    }
}

// ---------------------------------------------------------------------------
// Kernel 2: combine splits, gather quantize rows, write index-as-float.
// One thread per (row, float4-chunk): t in [0, N_ROWS*16).
// ---------------------------------------------------------------------------
__global__ void combine_kernel(const float* __restrict__ pbest,
                               const int* __restrict__ pidx,
                               const float* __restrict__ embed,
                               float* __restrict__ out) {
    const int t = blockIdx.x * blockDim.x + threadIdx.x;
    const int row = t >> 4;
    const int q = t & 15;
    if (row >= N_ROWS) return;

    float best = -INFINITY;
    int bi = 0;
#pragma unroll
    for (int s = 0; s < SPLITS; ++s) {
        float b = pbest[(size_t)s * N_ROWS + row];
        int i = pidx[(size_t)s * N_ROWS + row];
        if (b > best) {  // splits ascending in k; strict > keeps earliest
            best = b;
            bi = i;
        }
    }

    const float4* e4 = reinterpret_cast<const float4*>(embed);
    float4 v = e4[(size_t)bi * (DIM / 4) + q];
    reinterpret_cast<float4*>(out)[(size_t)row * (DIM / 4) + q] = v;
    if (q == 0) {
        out[(size_t)QUANT_ELEMS + row] = (float)bi;  // index as float
    }
}

// ---------------------------------------------------------------------------
extern "C" void kernel_launch(void* const* d_in, const int* in_sizes, int n_in,
                              void* d_out, int out_size, void* d_ws,
                              size_t ws_size, hipStream_t stream) {
    const float* x = (const float*)d_in[0];
    const float* embed = (const float*)d_in[1];
    float* out = (float*)d_out;

    // ws: sq 16KB | ehi 512KB | elo 512KB | pbest 512KB | pidx 512KB
    char* ws = (char*)d_ws;
    float* sq = (float*)ws;
    half8* ehi = (half8*)(ws + 16384);
    half8* elo = (half8*)(ws + 16384 + 524288);
    float* pbest = (float*)(ws + 16384 + 2 * 524288);
    int* pidx = (int*)(ws + 16384 + 2 * 524288 + SPLITS * N_ROWS * 4);

    prep_kernel<<<TILES_TOTAL, 256, 0, stream>>>(embed, sq, ehi, elo);

    dim3 grid(N_ROWS / 128, SPLITS);
    fused_dist_argmax_g<<<grid, 256, 0, stream>>>(x, sq, ehi, elo, pbest,
                                                  pidx);

    const int combine_threads = N_ROWS * (DIM / 4);
    combine_kernel<<<(combine_threads + 255) / 256, 256, 0, stream>>>(
        pbest, pidx, embed, out);
}